// Round 8
// baseline (189.572 us; speedup 1.0000x reference)
//
#include <hip/hip_runtime.h>
#include <hip/hip_bf16.h>

#define K_IN 256
#define O_OUT 64
#define NBINS 1024
#define NPB 49             // nodes per bin: 1024*49 = 50176 >= 50000
#define CAP 1824           // edges/bin capacity (mean 1562.5, +6.6 sigma)
#define PART_CHUNK 2048    // edges per partition block (8/thread)

typedef __attribute__((ext_vector_type(8))) short short8;
typedef __attribute__((ext_vector_type(4))) float f32x4;
typedef __attribute__((ext_vector_type(2))) unsigned u32x2;

// asm gather batch for sortagg (kept from R7 — correct there, and the
// gather results DO fit the 128-VGPR budget of that kernel).
#define GLOAD2(dst, base, voff)                                          \
  asm volatile("global_load_dwordx2 %0, %1, %2"                          \
               : "=v"(dst) : "v"(voff), "s"(base))
__device__ inline void vmwait0() {
  asm volatile("s_waitcnt vmcnt(0)" ::: "memory");
  __builtin_amdgcn_sched_barrier(0);
}

__device__ inline unsigned short bf16bits(float a) {
  __hip_bfloat16 t = __float2bfloat16(a);
  return *(unsigned short*)&t;
}

__device__ inline short8 cvt8(float4 f0, float4 f1) {
  short8 r;
  r[0] = (short)bf16bits(f0.x); r[1] = (short)bf16bits(f0.y);
  r[2] = (short)bf16bits(f0.z); r[3] = (short)bf16bits(f0.w);
  r[4] = (short)bf16bits(f1.x); r[5] = (short)bf16bits(f1.y);
  r[6] = (short)bf16bits(f1.z); r[7] = (short)bf16bits(f1.w);
  return r;
}

// ---------------- prep: W fp32 -> bf16 + zero cursor -------------
__global__ __launch_bounds__(256) void k_prep(const float* __restrict__ W,
                                              unsigned short* __restrict__ Wb,
                                              int* __restrict__ cursor) {
  int i = blockIdx.x * 256 + threadIdx.x;  // 64 blocks * 256 = 16384 exact
  Wb[i] = bf16bits(W[i]);
  if (i < NBINS) cursor[i] = 0;
}

// ---------------- part shared memory (16.4 KB, in-place scan) ----
struct PartSmem {
  int cntscan[NBINS];   // counts, then exclusive-scan in place
  int gbase[NBINS];
  int wsum[4];
  unsigned ord[PART_CHUNK];
};  // 4096+4096+16+8192 = 16400 B -> 8 blocks/CU (131 KB of 160)

// ---------------- GEMM body: one 64-node tile, NO LDS ------------
// A-frag: coalesced x loads (compiler-scheduled; TLP from 32 waves/CU
// hides latency). B-frag: straight from global Wb (32 KB, L2-hot;
// per-instr 16 lanes x 16 B contiguous per W row). No barrier at all.
__device__ void gemm_body(int gid, const float* __restrict__ x,
                          const unsigned short* __restrict__ Wb,
                          const float* __restrict__ bias,
                          __hip_bfloat16* __restrict__ h, int N) {
  const int tid = threadIdx.x;
  const int lane = tid & 63;
  const int wv = tid >> 6;
  const int n0 = gid * 64;

  int anode = n0 + wv * 16 + (lane & 15);
  if (anode > N - 1) anode = N - 1;  // clamp: stores guarded below
  const float* aptr = x + (size_t)anode * K_IN + (lane >> 4) * 8;
  const unsigned short* bptr = Wb + (lane & 15) * K_IN + (lane >> 4) * 8;

  f32x4 acc[4] = {{0.f, 0.f, 0.f, 0.f}, {0.f, 0.f, 0.f, 0.f},
                  {0.f, 0.f, 0.f, 0.f}, {0.f, 0.f, 0.f, 0.f}};
#pragma unroll
  for (int k8 = 0; k8 < 8; ++k8) {
    float4 f0 = *(const float4*)(aptr + k8 * 32);
    float4 f1 = *(const float4*)(aptr + k8 * 32 + 4);
    short8 a = cvt8(f0, f1);
#pragma unroll
    for (int nt = 0; nt < 4; ++nt) {
      short8 bfr = *(const short8*)(bptr + nt * 16 * K_IN + k8 * 32);
      acc[nt] = __builtin_amdgcn_mfma_f32_16x16x32_bf16(a, bfr, acc[nt], 0, 0, 0);
    }
  }

  // epilogue: bias + relu + bf16 store
  const int col = lane & 15;
  const int rbase = (lane >> 4) * 4;
#pragma unroll
  for (int nt = 0; nt < 4; ++nt) {
    float bv = bias[nt * 16 + col];
#pragma unroll
    for (int j = 0; j < 4; ++j) {
      int node = n0 + wv * 16 + rbase + j;
      if (node < N) {
        float v = fmaxf(acc[nt][j] + bv, 0.f);
        h[(size_t)node * O_OUT + nt * 16 + col] = __float2bfloat16(v);
      }
    }
  }
}

// ---------------- partition body (256 thr, 2048 edges) -----------
// bucket word: src[15:0] | dl[21:16] | bin[31:22]
__device__ void part_body(PartSmem& sm, int pid, const int* __restrict__ esrc,
                          const int* __restrict__ edst, int* __restrict__ cursor,
                          unsigned* __restrict__ bucket, int E) {
  const int tid = threadIdx.x;
  const int lane = tid & 63;
  const int wid = tid >> 6;
  const int base = pid * PART_CHUNK;

#pragma unroll
  for (int r = 0; r < 4; ++r) sm.cntscan[r * 256 + tid] = 0;

  int4 s4[2], d4[2];
#pragma unroll
  for (int r = 0; r < 2; ++r) {
    int e0 = base + r * 1024 + tid * 4;
    if (e0 > E - 4) e0 = E - 4;  // E%4==0: clamp, mask per-element below
    s4[r] = *(const int4*)(esrc + e0);
    d4[r] = *(const int4*)(edst + e0);
  }
  __syncthreads();  // cnt zeroing visible

  unsigned pk[8];
  int rk[8];
#pragma unroll
  for (int r = 0; r < 2; ++r) {
    const int* sp = (const int*)&s4[r];
    const int* dp = (const int*)&d4[r];
#pragma unroll
    for (int j = 0; j < 4; ++j) {
      int k = r * 4 + j;
      int e = base + r * 1024 + tid * 4 + j;
      if (e < E) {
        int d = dp[j];
        int bb = (int)__umulhi((unsigned)d, 87652394u);  // d / 49
        int dl = d - bb * NPB;
        pk[k] = ((unsigned)sp[j] & 0xFFFFu) | ((unsigned)dl << 16) |
                ((unsigned)bb << 22);
        rk[k] = atomicAdd(&sm.cntscan[bb], 1);
      } else {
        rk[k] = -1;
      }
    }
  }
  __syncthreads();

  // exclusive scan over 1024 bins IN PLACE: thread t owns bins 4t..4t+3
  int c0 = sm.cntscan[4 * tid];
  int c1 = sm.cntscan[4 * tid + 1];
  int c2 = sm.cntscan[4 * tid + 2];
  int c3 = sm.cntscan[4 * tid + 3];
  int s = c0 + c1 + c2 + c3;
  int incl = s;
#pragma unroll
  for (int off = 1; off < 64; off <<= 1) {
    int t = __shfl_up(incl, off);
    if (lane >= off) incl += t;
  }
  if (lane == 63) sm.wsum[wid] = incl;
  __syncthreads();
  int wpre = 0;
  for (int w = 0; w < wid; ++w) wpre += sm.wsum[w];
  int excl = wpre + incl - s;
  // same-thread read->write of same slots: no cross-thread hazard
  sm.cntscan[4 * tid] = excl;
  sm.cntscan[4 * tid + 1] = excl + c0;
  sm.cntscan[4 * tid + 2] = excl + c0 + c1;
  sm.cntscan[4 * tid + 3] = excl + c0 + c1 + c2;
  sm.gbase[4 * tid] = (c0 > 0) ? atomicAdd(&cursor[4 * tid], c0) : 0;
  sm.gbase[4 * tid + 1] = (c1 > 0) ? atomicAdd(&cursor[4 * tid + 1], c1) : 0;
  sm.gbase[4 * tid + 2] = (c2 > 0) ? atomicAdd(&cursor[4 * tid + 2], c2) : 0;
  sm.gbase[4 * tid + 3] = (c3 > 0) ? atomicAdd(&cursor[4 * tid + 3], c3) : 0;
  __syncthreads();

#pragma unroll
  for (int k = 0; k < 8; ++k) {
    if (rk[k] >= 0) {
      int bb = (int)(pk[k] >> 22);
      sm.ord[sm.cntscan[bb] + rk[k]] = pk[k];
    }
  }
  __syncthreads();

  int nv = E - base;
  if (nv > PART_CHUNK) nv = PART_CHUNK;
  for (int p = tid; p < nv; p += 256) {
    unsigned v = sm.ord[p];
    int bb = v >> 22;
    int slot = sm.gbase[bb] + (p - sm.cntscan[bb]);
    if (slot < CAP) bucket[(size_t)bb * CAP + slot] = v;
  }
}

// ---------------- fused heterogeneous dispatch -------------------
// ngemm = npart = 782 exactly: grid 1564, strict 1:1 interleave.
// LDS 16.4 KB + launch_bounds(256,8) -> 8 blocks/CU = 32 waves/CU.
__global__ __launch_bounds__(256, 8) void k_fused(const float* __restrict__ x,
                                                  const unsigned short* __restrict__ Wb,
                                                  const float* __restrict__ bias,
                                                  __hip_bfloat16* __restrict__ h,
                                                  const int* __restrict__ esrc,
                                                  const int* __restrict__ edst,
                                                  int* __restrict__ cursor,
                                                  unsigned* __restrict__ bucket,
                                                  int N, int E) {
  __shared__ PartSmem sm;
  const int b = blockIdx.x;
  if (b & 1) part_body(sm, b >> 1, esrc, edst, cursor, bucket, E);
  else gemm_body(b >> 1, x, Wb, bias, h, N);
}

// ---------------- fused per-bin sort + aggregate + normalize -----
// unchanged from R7 (passed; L3-BW-bound by the 205 MB h-gather stream)
__global__ __launch_bounds__(256, 4) void k_sortagg(const unsigned* __restrict__ bucket,
                                                    const int* __restrict__ cursor,
                                                    const unsigned* __restrict__ h32,
                                                    float* __restrict__ out, int N) {
  __shared__ int hist[NPB];
  __shared__ int offs[NPB];
  __shared__ unsigned short sbuf[CAP + 64];

  const int tid = threadIdx.x;
  const int lane = tid & 63;
  const int wid = tid >> 6;  // 0..3
  const int bin = blockIdx.x;

  if (tid < NPB) hist[tid] = 0;
  __syncthreads();

  int cnt = cursor[bin];
  if (cnt > CAP) cnt = CAP;
  const unsigned* bb = bucket + (size_t)bin * CAP;

  unsigned pk2[2][4];
  int rk2[2][4];
#pragma unroll
  for (int g = 0; g < 2; ++g) {
    int i0 = (g * 256 + tid) * 4;
    uint4 v;
    if (i0 + 3 < cnt) {
      v = *(const uint4*)(bb + i0);
    } else {
      v = make_uint4(0, 0, 0, 0);
      unsigned* vp = (unsigned*)&v;
      for (int j = 0; j < 4; ++j)
        if (i0 + j < cnt) vp[j] = bb[i0 + j];
    }
    const unsigned* vp = (const unsigned*)&v;
#pragma unroll
    for (int j = 0; j < 4; ++j) {
      if (i0 + j < cnt) {
        pk2[g][j] = vp[j];
        rk2[g][j] = atomicAdd(&hist[(vp[j] >> 16) & 63], 1);
      } else {
        rk2[g][j] = -1;
      }
    }
  }
  __syncthreads();

  // exclusive scan over 49 hist entries: wave 0 shfl-scan
  if (tid < 64) {
    int hval = (tid < NPB) ? hist[tid] : 0;
    int incl = hval;
#pragma unroll
    for (int off = 1; off < 64; off <<= 1) {
      int t = __shfl_up(incl, off);
      if (lane >= off) incl += t;
    }
    if (tid < NPB) offs[tid] = incl - hval;
  }
  __syncthreads();

#pragma unroll
  for (int g = 0; g < 2; ++g)
#pragma unroll
    for (int j = 0; j < 4; ++j)
      if (rk2[g][j] >= 0)
        sbuf[offs[(pk2[g][j] >> 16) & 63] + rk2[g][j]] =
            (unsigned short)(pk2[g][j] & 0xFFFFu);
  __syncthreads();

  // ---- aggregation: node pairs, 24 asm-forced quad-gathers ----
  const int q = lane >> 4;   // edge within quad
  const int hl = lane & 15;  // uint2 within h row
  const unsigned hlb = (unsigned)hl * 8u;

  for (int nl = wid; nl < NPB; nl += 8) {
    const int nlb = nl + 4;
    const bool hasb = (nlb < NPB);
    const int ca = hist[nl];
    const int cb = hasb ? hist[nlb] : 0;
    const unsigned short* bsa = sbuf + offs[nl];
    const unsigned short* bsb = sbuf + (hasb ? offs[nlb] : 0);

    unsigned voa[12], vob[12];
#pragma unroll
    for (int k = 0; k < 12; ++k) {
      int e = k * 4 + q;
      unsigned pa = (e < ca) ? (unsigned)bsa[e] : 0u;
      unsigned pb = (e < cb) ? (unsigned)bsb[e] : 0u;
      voa[k] = pa * 128u + hlb;
      vob[k] = pb * 128u + hlb;
    }
    u32x2 ua[12], ub[12];
#pragma unroll
    for (int k = 0; k < 12; ++k) { GLOAD2(ua[k], h32, voa[k]); }
#pragma unroll
    for (int k = 0; k < 12; ++k) { GLOAD2(ub[k], h32, vob[k]); }
    vmwait0();  // all 24 in flight, then consume

    float a0 = 0.f, a1 = 0.f, a2 = 0.f, a3 = 0.f;
    float b0 = 0.f, b1 = 0.f, b2 = 0.f, b3 = 0.f;
#pragma unroll
    for (int k = 0; k < 12; ++k) {
      float wk = (k * 4 + q < ca) ? 1.f : 0.f;
      a0 = fmaf(wk, __uint_as_float(ua[k][0] << 16), a0);
      a1 = fmaf(wk, __uint_as_float(ua[k][0] & 0xFFFF0000u), a1);
      a2 = fmaf(wk, __uint_as_float(ua[k][1] << 16), a2);
      a3 = fmaf(wk, __uint_as_float(ua[k][1] & 0xFFFF0000u), a3);
    }
#pragma unroll
    for (int k = 0; k < 12; ++k) {
      float wk = (k * 4 + q < cb) ? 1.f : 0.f;
      b0 = fmaf(wk, __uint_as_float(ub[k][0] << 16), b0);
      b1 = fmaf(wk, __uint_as_float(ub[k][0] & 0xFFFF0000u), b1);
      b2 = fmaf(wk, __uint_as_float(ub[k][1] << 16), b2);
      b3 = fmaf(wk, __uint_as_float(ub[k][1] & 0xFFFF0000u), b3);
    }

    // rare leftovers (c > 48): compiler loads
    const uint2* __restrict__ h2 = (const uint2*)h32;
    for (int e0 = 48; e0 < ca; e0 += 4) {
      int e = e0 + q;
      float wk = (e < ca) ? 1.f : 0.f;
      int p = (e < ca) ? (int)bsa[e] : 0;
      uint2 u = h2[(size_t)p * 16 + hl];
      a0 = fmaf(wk, __uint_as_float(u.x << 16), a0);
      a1 = fmaf(wk, __uint_as_float(u.x & 0xFFFF0000u), a1);
      a2 = fmaf(wk, __uint_as_float(u.y << 16), a2);
      a3 = fmaf(wk, __uint_as_float(u.y & 0xFFFF0000u), a3);
    }
    for (int e0 = 48; e0 < cb; e0 += 4) {
      int e = e0 + q;
      float wk = (e < cb) ? 1.f : 0.f;
      int p = (e < cb) ? (int)bsb[e] : 0;
      uint2 u = h2[(size_t)p * 16 + hl];
      b0 = fmaf(wk, __uint_as_float(u.x << 16), b0);
      b1 = fmaf(wk, __uint_as_float(u.x & 0xFFFF0000u), b1);
      b2 = fmaf(wk, __uint_as_float(u.y << 16), b2);
      b3 = fmaf(wk, __uint_as_float(u.y & 0xFFFF0000u), b3);
    }

    // butterflies (quad partials) + stores, both nodes
    a0 += __shfl_xor(a0, 16); a1 += __shfl_xor(a1, 16);
    a2 += __shfl_xor(a2, 16); a3 += __shfl_xor(a3, 16);
    b0 += __shfl_xor(b0, 16); b1 += __shfl_xor(b1, 16);
    b2 += __shfl_xor(b2, 16); b3 += __shfl_xor(b3, 16);
    a0 += __shfl_xor(a0, 32); a1 += __shfl_xor(a1, 32);
    a2 += __shfl_xor(a2, 32); a3 += __shfl_xor(a3, 32);
    b0 += __shfl_xor(b0, 32); b1 += __shfl_xor(b1, 32);
    b2 += __shfl_xor(b2, 32); b3 += __shfl_xor(b3, 32);

    if (lane < 16) {
      int na = bin * NPB + nl;
      if (na < N) {
        float inv = 1.f / fmaxf((float)ca, 1.f);
        float4 r;
        r.x = a0 * inv; r.y = a1 * inv; r.z = a2 * inv; r.w = a3 * inv;
        *(float4*)(out + (size_t)na * O_OUT + hl * 4) = r;
      }
      int nb = bin * NPB + nlb;
      if (hasb && nb < N) {
        float inv = 1.f / fmaxf((float)cb, 1.f);
        float4 r;
        r.x = b0 * inv; r.y = b1 * inv; r.z = b2 * inv; r.w = b3 * inv;
        *(float4*)(out + (size_t)nb * O_OUT + hl * 4) = r;
      }
    }
  }
}

// ---------------- launch -----------------------------------------
extern "C" void kernel_launch(void* const* d_in, const int* in_sizes, int n_in,
                              void* d_out, int out_size, void* d_ws, size_t ws_size,
                              hipStream_t stream) {
  const float* x = (const float*)d_in[0];
  const float* W = (const float*)d_in[1];
  const float* b = (const float*)d_in[2];
  const int* esrc = (const int*)d_in[3];
  const int* edst = (const int*)d_in[4];
  float* out = (float*)d_out;

  const int N = in_sizes[0] / K_IN;  // 50000
  const int E = in_sizes[3];         // 1600000

  // workspace layout (~13.9 MB)
  char* ws = (char*)d_ws;
  unsigned short* Wb = (unsigned short*)ws;                 // 32,768 B
  __hip_bfloat16* h = (__hip_bfloat16*)(ws + 32768);        // 6,400,000 B
  size_t off = 32768 + (size_t)N * O_OUT * sizeof(__hip_bfloat16);
  int* cursor = (int*)(ws + off);                           // 4,096 B
  off += NBINS * sizeof(int);
  unsigned* bucket = (unsigned*)(ws + off);                 // 7,471,104 B

  const int ngemm = (N + 63) / 64;                          // 782
  const int npart = (E + PART_CHUNK - 1) / PART_CHUNK;      // 782

  k_prep<<<(K_IN * O_OUT) / 256, 256, 0, stream>>>(W, Wb, cursor);
  k_fused<<<ngemm + npart, 256, 0, stream>>>(x, Wb, b, h, esrc, edst, cursor,
                                             bucket, N, E);
  k_sortagg<<<NBINS, 256, 0, stream>>>(bucket, cursor, (const unsigned*)h, out, N);
}

// Round 10
// 165.230 us; speedup vs baseline: 1.1473x; 1.1473x over previous
//
#include <hip/hip_runtime.h>
#include <hip/hip_bf16.h>

#define K_IN 256
#define O_OUT 64
#define NBINS 1024
#define NPB 49             // nodes per bin: 1024*49 = 50176 >= 50000
#define CAP 1824           // edges/bin capacity (mean 1562.5, +6.6 sigma)
#define PART_CHUNK 4096    // edges per partition block

typedef __attribute__((ext_vector_type(8))) short short8;
typedef __attribute__((ext_vector_type(4))) float f32x4;
typedef __attribute__((ext_vector_type(2))) unsigned u32x2;

// asm gather batch for sortagg (proven R7/R8)
#define GLOAD2(dst, base, voff)                                          \
  asm volatile("global_load_dwordx2 %0, %1, %2"                          \
               : "=v"(dst) : "v"(voff), "s"(base))
__device__ inline void vmwait0() {
  asm volatile("s_waitcnt vmcnt(0)" ::: "memory");
  __builtin_amdgcn_sched_barrier(0);
}

__device__ inline unsigned short bf16bits(float a) {
  __hip_bfloat16 t = __float2bfloat16(a);
  return *(unsigned short*)&t;
}

__device__ inline short8 cvt8(float4 f0, float4 f1) {
  short8 r;
  r[0] = (short)bf16bits(f0.x); r[1] = (short)bf16bits(f0.y);
  r[2] = (short)bf16bits(f0.z); r[3] = (short)bf16bits(f0.w);
  r[4] = (short)bf16bits(f1.x); r[5] = (short)bf16bits(f1.y);
  r[6] = (short)bf16bits(f1.z); r[7] = (short)bf16bits(f1.w);
  return r;
}

// ---------------- prep: W fp32 -> bf16 + zero cursor -------------
__global__ __launch_bounds__(256) void k_prep(const float* __restrict__ W,
                                              unsigned short* __restrict__ Wb,
                                              int* __restrict__ cursor) {
  int i = blockIdx.x * 256 + threadIdx.x;  // 64 blocks * 256 = 16384 exact
  Wb[i] = bf16bits(W[i]);
  if (i < NBINS) cursor[i] = 0;
}

// ---------------- shared-memory union for the fused kernel -------
// gemm: W 32 KB + x-tile 32 KB, both XOR-swizzled (byte ^= (row&7)<<4).
// x staged COALESCED (32 lanes x 32 B = 1 KB/row contiguous = 4 lines
// per wave-instr) -- fixes the 16-lines-per-instr TA divergence of the
// direct fragment load (the R5-R8 pole).
struct GemmSmem {
  unsigned short wsb[64 * 256];  // 32768 B
  unsigned short xs[64 * 256];   // 32768 B
};
struct PartSmem {
  int cnt[NBINS];
  int scanb[NBINS];
  int gbase[NBINS];
  int wsum[4];
  unsigned ord[PART_CHUNK];
};
union FusedSmem {
  GemmSmem g;
  PartSmem p;
};  // 65536 B -> 2 blocks/CU

// ---------------- GEMM body: one 64-node tile, 1 barrier ---------
__device__ void gemm_body(GemmSmem& sm, int gid, const float* __restrict__ x,
                          const unsigned short* __restrict__ Wb,
                          const float* __restrict__ bias,
                          __hip_bfloat16* __restrict__ h, int N) {
  const int tid = threadIdx.x;
  const int lane = tid & 63;
  const int wv = tid >> 6;
  const int n0 = gid * 64;

  // stage W: 32 KB coalesced uint4, swizzled
  {
    const uint4* wsrc = (const uint4*)Wb;  // 2048 uint4
#pragma unroll
    for (int r = 0; r < 8; ++r) {
      uint4 w = wsrc[r * 256 + tid];
      int flat = r * 256 + tid;
      int row = flat >> 5;
      int c16 = flat & 31;
      unsigned byte = (unsigned)(row * 512 + c16 * 16);
      byte ^= (unsigned)((row & 7) << 4);
      *(uint4*)((char*)sm.wsb + byte) = w;
    }
  }

  // stage x: 64 rows x 1 KB fp32, coalesced (32 lanes cover one row),
  // cvt to bf16, swizzled LDS write (16 B per thread per r)
  {
#pragma unroll
    for (int r = 0; r < 8; ++r) {
      int c = r * 256 + tid;        // 16B-bf16-chunk id, 2048 total
      int row = c >> 5;             // 32 chunks per row
      int c16 = c & 31;
      int node = n0 + row;
      if (node > N - 1) node = N - 1;   // clamp; stores guarded below
      const float4* ps = (const float4*)(x + (size_t)node * K_IN + c16 * 8);
      float4 f0 = ps[0];
      float4 f1 = ps[1];
      unsigned byte = (unsigned)(row * 512 + c16 * 16);
      byte ^= (unsigned)((row & 7) << 4);
      *(short8*)((char*)sm.xs + byte) = cvt8(f0, f1);
    }
  }
  __syncthreads();

  const int brow0 = lane & 15;
  const unsigned kb = (unsigned)((lane >> 4) * 16);
  const unsigned bswz = (unsigned)((brow0 & 7) << 4);
  const int arow = wv * 16 + (lane & 15);
  const unsigned aswz = (unsigned)((arow & 7) << 4);
  const unsigned abase = (unsigned)(arow * 512) + kb;

  f32x4 acc[4] = {{0.f, 0.f, 0.f, 0.f}, {0.f, 0.f, 0.f, 0.f},
                  {0.f, 0.f, 0.f, 0.f}, {0.f, 0.f, 0.f, 0.f}};
#pragma unroll
  for (int k8 = 0; k8 < 8; ++k8) {
    unsigned ab = (abase + (unsigned)(k8 * 64)) ^ aswz;
    short8 a = *(const short8*)((const char*)sm.xs + ab);
#pragma unroll
    for (int nt = 0; nt < 4; ++nt) {
      unsigned byte = (unsigned)((brow0 + nt * 16) * 512 + k8 * 64) + kb;
      byte ^= bswz;
      short8 bfr = *(const short8*)((const char*)sm.wsb + byte);
      acc[nt] = __builtin_amdgcn_mfma_f32_16x16x32_bf16(a, bfr, acc[nt], 0, 0, 0);
    }
  }

  // epilogue: bias + relu + bf16 store
  const int col = lane & 15;
  const int rbase = (lane >> 4) * 4;
#pragma unroll
  for (int nt = 0; nt < 4; ++nt) {
    float bv = bias[nt * 16 + col];
#pragma unroll
    for (int j = 0; j < 4; ++j) {
      int node = n0 + wv * 16 + rbase + j;
      if (node < N) {
        float v = fmaxf(acc[nt][j] + bv, 0.f);
        h[(size_t)node * O_OUT + nt * 16 + col] = __float2bfloat16(v);
      }
    }
  }
}

// ---------------- partition body (256 thr, 4096 edges) -----------
// bucket word: src[15:0] | dl[21:16] | bin[31:22]  (R5, proven)
__device__ void part_body(PartSmem& sm, int pid, const int* __restrict__ esrc,
                          const int* __restrict__ edst, int* __restrict__ cursor,
                          unsigned* __restrict__ bucket, int E) {
  const int tid = threadIdx.x;
  const int lane = tid & 63;
  const int wid = tid >> 6;
  const int base = pid * PART_CHUNK;

#pragma unroll
  for (int r = 0; r < 4; ++r) sm.cnt[r * 256 + tid] = 0;

  int4 s4[4], d4[4];
#pragma unroll
  for (int r = 0; r < 4; ++r) {
    int e0 = base + r * 1024 + tid * 4;
    if (e0 + 3 < E) {
      s4[r] = *(const int4*)(esrc + e0);
      d4[r] = *(const int4*)(edst + e0);
    } else {
      s4[r] = make_int4(0, 0, 0, 0);
      d4[r] = make_int4(0, 0, 0, 0);
      int* sp = (int*)&s4[r];
      int* dp = (int*)&d4[r];
      for (int j = 0; j < 4; ++j)
        if (e0 + j < E) { sp[j] = esrc[e0 + j]; dp[j] = edst[e0 + j]; }
    }
  }
  __syncthreads();  // cnt zeroing visible

  unsigned pk[16];
  int rk[16];
#pragma unroll
  for (int r = 0; r < 4; ++r) {
    const int* sp = (const int*)&s4[r];
    const int* dp = (const int*)&d4[r];
#pragma unroll
    for (int j = 0; j < 4; ++j) {
      int k = r * 4 + j;
      int e = base + r * 1024 + tid * 4 + j;
      if (e < E) {
        int d = dp[j];
        int bb = (int)__umulhi((unsigned)d, 87652394u);  // d / 49
        int dl = d - bb * NPB;
        pk[k] = ((unsigned)sp[j] & 0xFFFFu) | ((unsigned)dl << 16) |
                ((unsigned)bb << 22);
        rk[k] = atomicAdd(&sm.cnt[bb], 1);
      } else {
        rk[k] = -1;
      }
    }
  }
  __syncthreads();

  // exclusive scan over 1024 bins: thread t owns bins 4t..4t+3
  int c0 = sm.cnt[4 * tid];
  int c1 = sm.cnt[4 * tid + 1];
  int c2 = sm.cnt[4 * tid + 2];
  int c3 = sm.cnt[4 * tid + 3];
  int s = c0 + c1 + c2 + c3;
  int incl = s;
#pragma unroll
  for (int off = 1; off < 64; off <<= 1) {
    int t = __shfl_up(incl, off);
    if (lane >= off) incl += t;
  }
  if (lane == 63) sm.wsum[wid] = incl;
  __syncthreads();
  int wpre = 0;
  for (int w = 0; w < wid; ++w) wpre += sm.wsum[w];
  int excl = wpre + incl - s;
  sm.scanb[4 * tid] = excl;
  sm.scanb[4 * tid + 1] = excl + c0;
  sm.scanb[4 * tid + 2] = excl + c0 + c1;
  sm.scanb[4 * tid + 3] = excl + c0 + c1 + c2;
  sm.gbase[4 * tid] = (c0 > 0) ? atomicAdd(&cursor[4 * tid], c0) : 0;
  sm.gbase[4 * tid + 1] = (c1 > 0) ? atomicAdd(&cursor[4 * tid + 1], c1) : 0;
  sm.gbase[4 * tid + 2] = (c2 > 0) ? atomicAdd(&cursor[4 * tid + 2], c2) : 0;
  sm.gbase[4 * tid + 3] = (c3 > 0) ? atomicAdd(&cursor[4 * tid + 3], c3) : 0;
  __syncthreads();

#pragma unroll
  for (int k = 0; k < 16; ++k) {
    if (rk[k] >= 0) {
      int bb = (int)(pk[k] >> 22);
      sm.ord[sm.scanb[bb] + rk[k]] = pk[k];
    }
  }
  __syncthreads();

  int nv = E - base;
  if (nv > PART_CHUNK) nv = PART_CHUNK;
  for (int p = tid; p < nv; p += 256) {
    unsigned v = sm.ord[p];
    int bb = v >> 22;
    int slot = sm.gbase[bb] + (p - sm.scanb[bb]);
    if (slot < CAP) bucket[(size_t)bb * CAP + slot] = v;
  }
}

// ---------------- fused heterogeneous dispatch -------------------
// 2:1 interleave: blockIdx%3==1 -> partition, else GEMM.
// LDS 64 KB -> 2 blocks/CU; launch_bounds(256,2) -> VGPR cap 256 (no spill).
__global__ __launch_bounds__(256, 2) void k_fused(const float* __restrict__ x,
                                                  const unsigned short* __restrict__ Wb,
                                                  const float* __restrict__ bias,
                                                  __hip_bfloat16* __restrict__ h,
                                                  const int* __restrict__ esrc,
                                                  const int* __restrict__ edst,
                                                  int* __restrict__ cursor,
                                                  unsigned* __restrict__ bucket,
                                                  int N, int E) {
  __shared__ FusedSmem sm;
  const int npart = (E + PART_CHUNK - 1) / PART_CHUNK;
  const int b = blockIdx.x;
  if (b % 3 == 1 && b / 3 < npart) {
    part_body(sm.p, b / 3, esrc, edst, cursor, bucket, E);
  } else {
    int skipped = (b + 2) / 3;
    if (skipped > npart) skipped = npart;
    gemm_body(sm.g, b - skipped, x, Wb, bias, h, N);
  }
}

// ---------------- fused per-bin sort + aggregate + normalize -----
// (R7, proven) node pairs; 24 gathers asm-batched per iteration.
__global__ __launch_bounds__(256, 4) void k_sortagg(const unsigned* __restrict__ bucket,
                                                    const int* __restrict__ cursor,
                                                    const unsigned* __restrict__ h32,
                                                    float* __restrict__ out, int N) {
  __shared__ int hist[NPB];
  __shared__ int offs[NPB];
  __shared__ unsigned short sbuf[CAP + 64];

  const int tid = threadIdx.x;
  const int lane = tid & 63;
  const int wid = tid >> 6;  // 0..3
  const int bin = blockIdx.x;

  if (tid < NPB) hist[tid] = 0;
  __syncthreads();

  int cnt = cursor[bin];
  if (cnt > CAP) cnt = CAP;
  const unsigned* bb = bucket + (size_t)bin * CAP;

  unsigned pk2[2][4];
  int rk2[2][4];
#pragma unroll
  for (int g = 0; g < 2; ++g) {
    int i0 = (g * 256 + tid) * 4;
    uint4 v;
    if (i0 + 3 < cnt) {
      v = *(const uint4*)(bb + i0);
    } else {
      v = make_uint4(0, 0, 0, 0);
      unsigned* vp = (unsigned*)&v;
      for (int j = 0; j < 4; ++j)
        if (i0 + j < cnt) vp[j] = bb[i0 + j];
    }
    const unsigned* vp = (const unsigned*)&v;
#pragma unroll
    for (int j = 0; j < 4; ++j) {
      if (i0 + j < cnt) {
        pk2[g][j] = vp[j];
        rk2[g][j] = atomicAdd(&hist[(vp[j] >> 16) & 63], 1);
      } else {
        rk2[g][j] = -1;
      }
    }
  }
  __syncthreads();

  if (tid < 64) {
    int hval = (tid < NPB) ? hist[tid] : 0;
    int incl = hval;
#pragma unroll
    for (int off = 1; off < 64; off <<= 1) {
      int t = __shfl_up(incl, off);
      if (lane >= off) incl += t;
    }
    if (tid < NPB) offs[tid] = incl - hval;
  }
  __syncthreads();

#pragma unroll
  for (int g = 0; g < 2; ++g)
#pragma unroll
    for (int j = 0; j < 4; ++j)
      if (rk2[g][j] >= 0)
        sbuf[offs[(pk2[g][j] >> 16) & 63] + rk2[g][j]] =
            (unsigned short)(pk2[g][j] & 0xFFFFu);
  __syncthreads();

  const int q = lane >> 4;   // edge within quad
  const int hl = lane & 15;  // uint2 within h row
  const unsigned hlb = (unsigned)hl * 8u;

  for (int nl = wid; nl < NPB; nl += 8) {
    const int nlb = nl + 4;
    const bool hasb = (nlb < NPB);
    const int ca = hist[nl];
    const int cb = hasb ? hist[nlb] : 0;
    const unsigned short* bsa = sbuf + offs[nl];
    const unsigned short* bsb = sbuf + (hasb ? offs[nlb] : 0);

    unsigned voa[12], vob[12];
#pragma unroll
    for (int k = 0; k < 12; ++k) {
      int e = k * 4 + q;
      unsigned pa = (e < ca) ? (unsigned)bsa[e] : 0u;
      unsigned pb = (e < cb) ? (unsigned)bsb[e] : 0u;
      voa[k] = pa * 128u + hlb;
      vob[k] = pb * 128u + hlb;
    }
    u32x2 ua[12], ub[12];
#pragma unroll
    for (int k = 0; k < 12; ++k) { GLOAD2(ua[k], h32, voa[k]); }
#pragma unroll
    for (int k = 0; k < 12; ++k) { GLOAD2(ub[k], h32, vob[k]); }
    vmwait0();

    float a0 = 0.f, a1 = 0.f, a2 = 0.f, a3 = 0.f;
    float b0 = 0.f, b1 = 0.f, b2 = 0.f, b3 = 0.f;
#pragma unroll
    for (int k = 0; k < 12; ++k) {
      float wk = (k * 4 + q < ca) ? 1.f : 0.f;
      a0 = fmaf(wk, __uint_as_float(ua[k][0] << 16), a0);
      a1 = fmaf(wk, __uint_as_float(ua[k][0] & 0xFFFF0000u), a1);
      a2 = fmaf(wk, __uint_as_float(ua[k][1] << 16), a2);
      a3 = fmaf(wk, __uint_as_float(ua[k][1] & 0xFFFF0000u), a3);
    }
#pragma unroll
    for (int k = 0; k < 12; ++k) {
      float wk = (k * 4 + q < cb) ? 1.f : 0.f;
      b0 = fmaf(wk, __uint_as_float(ub[k][0] << 16), b0);
      b1 = fmaf(wk, __uint_as_float(ub[k][0] & 0xFFFF0000u), b1);
      b2 = fmaf(wk, __uint_as_float(ub[k][1] << 16), b2);
      b3 = fmaf(wk, __uint_as_float(ub[k][1] & 0xFFFF0000u), b3);
    }

    const uint2* __restrict__ h2 = (const uint2*)h32;
    for (int e0 = 48; e0 < ca; e0 += 4) {
      int e = e0 + q;
      float wk = (e < ca) ? 1.f : 0.f;
      int p = (e < ca) ? (int)bsa[e] : 0;
      uint2 u = h2[(size_t)p * 16 + hl];
      a0 = fmaf(wk, __uint_as_float(u.x << 16), a0);
      a1 = fmaf(wk, __uint_as_float(u.x & 0xFFFF0000u), a1);
      a2 = fmaf(wk, __uint_as_float(u.y << 16), a2);
      a3 = fmaf(wk, __uint_as_float(u.y & 0xFFFF0000u), a3);
    }
    for (int e0 = 48; e0 < cb; e0 += 4) {
      int e = e0 + q;
      float wk = (e < cb) ? 1.f : 0.f;
      int p = (e < cb) ? (int)bsb[e] : 0;
      uint2 u = h2[(size_t)p * 16 + hl];
      b0 = fmaf(wk, __uint_as_float(u.x << 16), b0);
      b1 = fmaf(wk, __uint_as_float(u.x & 0xFFFF0000u), b1);
      b2 = fmaf(wk, __uint_as_float(u.y << 16), b2);
      b3 = fmaf(wk, __uint_as_float(u.y & 0xFFFF0000u), b3);
    }

    a0 += __shfl_xor(a0, 16); a1 += __shfl_xor(a1, 16);
    a2 += __shfl_xor(a2, 16); a3 += __shfl_xor(a3, 16);
    b0 += __shfl_xor(b0, 16); b1 += __shfl_xor(b1, 16);
    b2 += __shfl_xor(b2, 16); b3 += __shfl_xor(b3, 16);
    a0 += __shfl_xor(a0, 32); a1 += __shfl_xor(a1, 32);
    a2 += __shfl_xor(a2, 32); a3 += __shfl_xor(a3, 32);
    b0 += __shfl_xor(b0, 32); b1 += __shfl_xor(b1, 32);
    b2 += __shfl_xor(b2, 32); b3 += __shfl_xor(b3, 32);

    if (lane < 16) {
      int na = bin * NPB + nl;
      if (na < N) {
        float inv = 1.f / fmaxf((float)ca, 1.f);
        float4 r;
        r.x = a0 * inv; r.y = a1 * inv; r.z = a2 * inv; r.w = a3 * inv;
        *(float4*)(out + (size_t)na * O_OUT + hl * 4) = r;
      }
      int nb = bin * NPB + nlb;
      if (hasb && nb < N) {
        float inv = 1.f / fmaxf((float)cb, 1.f);
        float4 r;
        r.x = b0 * inv; r.y = b1 * inv; r.z = b2 * inv; r.w = b3 * inv;
        *(float4*)(out + (size_t)nb * O_OUT + hl * 4) = r;
      }
    }
  }
}

// ---------------- launch -----------------------------------------
extern "C" void kernel_launch(void* const* d_in, const int* in_sizes, int n_in,
                              void* d_out, int out_size, void* d_ws, size_t ws_size,
                              hipStream_t stream) {
  const float* x = (const float*)d_in[0];
  const float* W = (const float*)d_in[1];
  const float* b = (const float*)d_in[2];
  const int* esrc = (const int*)d_in[3];
  const int* edst = (const int*)d_in[4];
  float* out = (float*)d_out;

  const int N = in_sizes[0] / K_IN;  // 50000
  const int E = in_sizes[3];         // 1600000

  // workspace layout (~13.9 MB)
  char* ws = (char*)d_ws;
  unsigned short* Wb = (unsigned short*)ws;                 // 32,768 B
  __hip_bfloat16* h = (__hip_bfloat16*)(ws + 32768);        // 6,400,000 B
  size_t off = 32768 + (size_t)N * O_OUT * sizeof(__hip_bfloat16);
  int* cursor = (int*)(ws + off);                           // 4,096 B
  off += NBINS * sizeof(int);
  unsigned* bucket = (unsigned*)(ws + off);                 // 7,471,104 B

  const int ngemm = (N + 63) / 64;                          // 782
  const int npart = (E + PART_CHUNK - 1) / PART_CHUNK;      // 391

  k_prep<<<(K_IN * O_OUT) / 256, 256, 0, stream>>>(W, Wb, cursor);
  k_fused<<<ngemm + npart, 256, 0, stream>>>(x, Wb, b, h, esrc, edst, cursor,
                                             bucket, N, E);
  k_sortagg<<<NBINS, 256, 0, stream>>>(bucket, cursor, (const unsigned*)h, out, N);
}

// Round 11
// 150.990 us; speedup vs baseline: 1.2555x; 1.0943x over previous
//
#include <hip/hip_runtime.h>
#include <hip/hip_bf16.h>

#define K_IN 256
#define O_OUT 64
#define NBINS 1024
#define NPB 49             // nodes per bin: 1024*49 = 50176 >= 50000
#define CAP 1824           // edges/bin capacity (mean 1562.5, +6.6 sigma)
#define PART_CHUNK 4096    // edges per partition block
#define SCAN_STRIDE 1026   // u16 entries per pid in scan_tab (1025 + pad)

typedef __attribute__((ext_vector_type(8))) short short8;
typedef __attribute__((ext_vector_type(4))) float f32x4;
typedef __attribute__((ext_vector_type(2))) unsigned u32x2;

// asm gather batch for sortagg (proven R7/R8/R10)
#define GLOAD2(dst, base, voff)                                          \
  asm volatile("global_load_dwordx2 %0, %1, %2"                          \
               : "=v"(dst) : "v"(voff), "s"(base))
__device__ inline void vmwait0() {
  asm volatile("s_waitcnt vmcnt(0)" ::: "memory");
  __builtin_amdgcn_sched_barrier(0);
}

__device__ inline unsigned short bf16bits(float a) {
  __hip_bfloat16 t = __float2bfloat16(a);
  return *(unsigned short*)&t;
}

__device__ inline short8 cvt8(float4 f0, float4 f1) {
  short8 r;
  r[0] = (short)bf16bits(f0.x); r[1] = (short)bf16bits(f0.y);
  r[2] = (short)bf16bits(f0.z); r[3] = (short)bf16bits(f0.w);
  r[4] = (short)bf16bits(f1.x); r[5] = (short)bf16bits(f1.y);
  r[6] = (short)bf16bits(f1.z); r[7] = (short)bf16bits(f1.w);
  return r;
}

// ---------------- shared-memory union for the fused kernel -------
struct GemmSmem {
  unsigned short wsb[64 * 256];  // 32768 B, byte ^= (row&7)<<4 swizzle
};
struct PartSmem {
  int cnt[NBINS];
  int scanb[NBINS];
  int wsum[4];
  unsigned ord[PART_CHUNK];
};  // 24592 B
union FusedSmem {
  GemmSmem g;
  PartSmem p;
};  // 32768 B -> 4+ blocks/CU

// ---------------- GEMM body (R5-proven form, W cvt inline) -------
// A-frag direct from global x; B-frag from swizzled LDS W (fp32 read,
// bf16 cvt during staging -> k_prep eliminated).
__device__ void gemm_body(GemmSmem& sm, int gid, const float* __restrict__ x,
                          const float* __restrict__ W,
                          const float* __restrict__ bias,
                          __hip_bfloat16* __restrict__ h, int N) {
  const int tid = threadIdx.x;
  const int lane = tid & 63;
  const int wv = tid >> 6;
  const int n0 = gid * 64;

  // stage W: 64 KB fp32 coalesced, cvt to bf16, swizzled 16 B stores
  {
#pragma unroll
    for (int r = 0; r < 8; ++r) {
      int c = r * 256 + tid;               // 8-float chunk id (2048 total)
      const float4* ps = (const float4*)(W + c * 8);
      float4 f0 = ps[0];
      float4 f1 = ps[1];
      int row = c >> 5;
      int c16 = c & 31;
      unsigned byte = (unsigned)(row * 512 + c16 * 16);
      byte ^= (unsigned)((row & 7) << 4);
      *(short8*)((char*)sm.wsb + byte) = cvt8(f0, f1);
    }
  }
  __syncthreads();

  int anode = n0 + wv * 16 + (lane & 15);
  if (anode > N - 1) anode = N - 1;  // clamp: stores guarded below
  const float* aptr = x + (size_t)anode * K_IN + (lane >> 4) * 8;

  const int brow0 = lane & 15;
  const unsigned kb = (unsigned)((lane >> 4) * 16);
  const unsigned bswz = (unsigned)((brow0 & 7) << 4);

  f32x4 acc[4] = {{0.f, 0.f, 0.f, 0.f}, {0.f, 0.f, 0.f, 0.f},
                  {0.f, 0.f, 0.f, 0.f}, {0.f, 0.f, 0.f, 0.f}};
#pragma unroll
  for (int k8 = 0; k8 < 8; ++k8) {
    float4 f0 = *(const float4*)(aptr + k8 * 32);
    float4 f1 = *(const float4*)(aptr + k8 * 32 + 4);
    short8 a = cvt8(f0, f1);
#pragma unroll
    for (int nt = 0; nt < 4; ++nt) {
      unsigned byte = (unsigned)((brow0 + nt * 16) * 512 + k8 * 64) + kb;
      byte ^= bswz;
      short8 bfr = *(const short8*)((const char*)sm.wsb + byte);
      acc[nt] = __builtin_amdgcn_mfma_f32_16x16x32_bf16(a, bfr, acc[nt], 0, 0, 0);
    }
  }

  // epilogue: bias + relu + bf16 store
  const int col = lane & 15;
  const int rbase = (lane >> 4) * 4;
#pragma unroll
  for (int nt = 0; nt < 4; ++nt) {
    float bv = bias[nt * 16 + col];
#pragma unroll
    for (int j = 0; j < 4; ++j) {
      int node = n0 + wv * 16 + rbase + j;
      if (node < N) {
        float v = fmaxf(acc[nt][j] + bv, 0.f);
        h[(size_t)node * O_OUT + nt * 16 + col] = __float2bfloat16(v);
      }
    }
  }
}

// ---------------- partition body: DETERMINISTIC output -----------
// Block pid sorts its 4096 edges by bin in LDS, then writes them
// CONTIGUOUSLY at bucket_det[pid*4096] (coalesced) + its u16 prefix
// table scan_tab[pid][0..1024]. NO global atomics, NO cursor.
// word: src[15:0] | dl[21:16] | bin[31:22]
__device__ void part_body(PartSmem& sm, int pid, const int* __restrict__ esrc,
                          const int* __restrict__ edst,
                          unsigned* __restrict__ bucket_det,
                          unsigned short* __restrict__ scan_tab, int E) {
  const int tid = threadIdx.x;
  const int lane = tid & 63;
  const int wid = tid >> 6;
  const int base = pid * PART_CHUNK;

#pragma unroll
  for (int r = 0; r < 4; ++r) sm.cnt[r * 256 + tid] = 0;

  int4 s4[4], d4[4];
#pragma unroll
  for (int r = 0; r < 4; ++r) {
    int e0 = base + r * 1024 + tid * 4;
    if (e0 + 3 < E) {
      s4[r] = *(const int4*)(esrc + e0);
      d4[r] = *(const int4*)(edst + e0);
    } else {
      s4[r] = make_int4(0, 0, 0, 0);
      d4[r] = make_int4(0, 0, 0, 0);
      int* sp = (int*)&s4[r];
      int* dp = (int*)&d4[r];
      for (int j = 0; j < 4; ++j)
        if (e0 + j < E) { sp[j] = esrc[e0 + j]; dp[j] = edst[e0 + j]; }
    }
  }
  __syncthreads();  // cnt zeroing visible

  unsigned pk[16];
  int rk[16];
#pragma unroll
  for (int r = 0; r < 4; ++r) {
    const int* sp = (const int*)&s4[r];
    const int* dp = (const int*)&d4[r];
#pragma unroll
    for (int j = 0; j < 4; ++j) {
      int k = r * 4 + j;
      int e = base + r * 1024 + tid * 4 + j;
      if (e < E) {
        int d = dp[j];
        int bb = (int)__umulhi((unsigned)d, 87652394u);  // d / 49
        int dl = d - bb * NPB;
        pk[k] = ((unsigned)sp[j] & 0xFFFFu) | ((unsigned)dl << 16) |
                ((unsigned)bb << 22);
        rk[k] = atomicAdd(&sm.cnt[bb], 1);
      } else {
        rk[k] = -1;
      }
    }
  }
  __syncthreads();

  // exclusive scan over 1024 bins: thread t owns bins 4t..4t+3
  int c0 = sm.cnt[4 * tid];
  int c1 = sm.cnt[4 * tid + 1];
  int c2 = sm.cnt[4 * tid + 2];
  int c3 = sm.cnt[4 * tid + 3];
  int s = c0 + c1 + c2 + c3;
  int incl = s;
#pragma unroll
  for (int off = 1; off < 64; off <<= 1) {
    int t = __shfl_up(incl, off);
    if (lane >= off) incl += t;
  }
  if (lane == 63) sm.wsum[wid] = incl;
  __syncthreads();
  int wpre = 0;
  for (int w = 0; w < wid; ++w) wpre += sm.wsum[w];
  int excl = wpre + incl - s;
  sm.scanb[4 * tid] = excl;
  sm.scanb[4 * tid + 1] = excl + c0;
  sm.scanb[4 * tid + 2] = excl + c0 + c1;
  sm.scanb[4 * tid + 3] = excl + c0 + c1 + c2;
  __syncthreads();

#pragma unroll
  for (int k = 0; k < 16; ++k) {
    if (rk[k] >= 0) {
      int bb = (int)(pk[k] >> 22);
      sm.ord[sm.scanb[bb] + rk[k]] = pk[k];
    }
  }
  __syncthreads();

  int nv = E - base;
  if (nv > PART_CHUNK) nv = PART_CHUNK;

  // coalesced global writes: sorted edges + u16 prefix table
  unsigned* dstp = bucket_det + (size_t)pid * PART_CHUNK;
  for (int p = tid; p < nv; p += 256) dstp[p] = sm.ord[p];
  unsigned short* st = scan_tab + (size_t)pid * SCAN_STRIDE;
  for (int i = tid; i < NBINS; i += 256) st[i] = (unsigned short)sm.scanb[i];
  if (tid == 0) st[NBINS] = (unsigned short)nv;
}

// ---------------- fused heterogeneous dispatch -------------------
// 2:1 interleave: blockIdx%3==1 -> partition, else GEMM.
__global__ __launch_bounds__(256, 4) void k_fused(const float* __restrict__ x,
                                                  const float* __restrict__ W,
                                                  const float* __restrict__ bias,
                                                  __hip_bfloat16* __restrict__ h,
                                                  const int* __restrict__ esrc,
                                                  const int* __restrict__ edst,
                                                  unsigned* __restrict__ bucket_det,
                                                  unsigned short* __restrict__ scan_tab,
                                                  int N, int E) {
  __shared__ FusedSmem sm;
  const int npart = (E + PART_CHUNK - 1) / PART_CHUNK;
  const int b = blockIdx.x;
  if (b % 3 == 1 && b / 3 < npart) {
    part_body(sm.p, b / 3, esrc, edst, bucket_det, scan_tab, E);
  } else {
    int skipped = (b + 2) / 3;
    if (skipped > npart) skipped = npart;
    gemm_body(sm.g, b - skipped, x, W, bias, h, N);
  }
}

// ---------------- per-bin segmented gather + sort + aggregate ----
// Phase 1: collect bin's edges from the 391 per-block segments into
// LDS (order-free wave-atomic placement). Phase 2: R7-proven
// hist/scan/scatter + asm-batched h-gather.
__global__ __launch_bounds__(256, 4) void k_sortagg(const unsigned* __restrict__ bucket_det,
                                                    const unsigned short* __restrict__ scan_tab,
                                                    const unsigned* __restrict__ h32,
                                                    float* __restrict__ out,
                                                    int N, int npart) {
  __shared__ unsigned ord32[CAP];
  __shared__ int segbase;
  __shared__ int hist[NPB];
  __shared__ int offs[NPB];
  __shared__ unsigned short sbuf[CAP + 64];

  const int tid = threadIdx.x;
  const int lane = tid & 63;
  const int wid = tid >> 6;  // 0..3
  const int bin = blockIdx.x;

  if (tid == 0) segbase = 0;
  if (tid < NPB) hist[tid] = 0;
  __syncthreads();

  // phase 1: segmented copy, 2 rounds of 256 pids
#pragma unroll
  for (int r = 0; r < 2; ++r) {
    int p = r * 256 + tid;
    int cnt_p = 0, s = 0;
    if (p < npart) {
      const unsigned short* st = scan_tab + (size_t)p * SCAN_STRIDE;
      s = st[bin];
      int e = st[bin + 1];
      cnt_p = e - s;
    }
    // wave-level placement: shfl prefix + one LDS atomic per wave
    int incl = cnt_p;
#pragma unroll
    for (int off = 1; off < 64; off <<= 1) {
      int t = __shfl_up(incl, off);
      if (lane >= off) incl += t;
    }
    int base_w = 0;
    if (lane == 63) base_w = atomicAdd(&segbase, incl);
    base_w = __shfl(base_w, 63);
    int myofs = base_w + incl - cnt_p;
    const unsigned* srcp = bucket_det + (size_t)p * PART_CHUNK + s;
    for (int j = 0; j < cnt_p; ++j)
      if (myofs + j < CAP) ord32[myofs + j] = srcp[j];
  }
  __syncthreads();

  int cnt = segbase;
  if (cnt > CAP) cnt = CAP;

  // phase 2a: histogram by dst-local (from LDS list)
  unsigned pk2[2][4];
  int rk2[2][4];
#pragma unroll
  for (int g = 0; g < 2; ++g) {
#pragma unroll
    for (int j = 0; j < 4; ++j) {
      int i = (g * 256 + tid) * 4 + j;
      if (i < cnt) {
        unsigned w = ord32[i];
        pk2[g][j] = w;
        rk2[g][j] = atomicAdd(&hist[(w >> 16) & 63], 1);
      } else {
        rk2[g][j] = -1;
      }
    }
  }
  __syncthreads();

  // phase 2b: exclusive scan over 49 hist entries (wave 0)
  if (tid < 64) {
    int hval = (tid < NPB) ? hist[tid] : 0;
    int incl = hval;
#pragma unroll
    for (int off = 1; off < 64; off <<= 1) {
      int t = __shfl_up(incl, off);
      if (lane >= off) incl += t;
    }
    if (tid < NPB) offs[tid] = incl - hval;
  }
  __syncthreads();

#pragma unroll
  for (int g = 0; g < 2; ++g)
#pragma unroll
    for (int j = 0; j < 4; ++j)
      if (rk2[g][j] >= 0)
        sbuf[offs[(pk2[g][j] >> 16) & 63] + rk2[g][j]] =
            (unsigned short)(pk2[g][j] & 0xFFFFu);
  __syncthreads();

  // phase 2c: gather + accumulate (node pairs, asm-batched)
  const int q = lane >> 4;   // edge within quad
  const int hl = lane & 15;  // uint2 within h row
  const unsigned hlb = (unsigned)hl * 8u;

  for (int nl = wid; nl < NPB; nl += 8) {
    const int nlb = nl + 4;
    const bool hasb = (nlb < NPB);
    const int ca = hist[nl];
    const int cb = hasb ? hist[nlb] : 0;
    const unsigned short* bsa = sbuf + offs[nl];
    const unsigned short* bsb = sbuf + (hasb ? offs[nlb] : 0);

    unsigned voa[12], vob[12];
#pragma unroll
    for (int k = 0; k < 12; ++k) {
      int e = k * 4 + q;
      unsigned pa = (e < ca) ? (unsigned)bsa[e] : 0u;
      unsigned pb = (e < cb) ? (unsigned)bsb[e] : 0u;
      voa[k] = pa * 128u + hlb;
      vob[k] = pb * 128u + hlb;
    }
    u32x2 ua[12], ub[12];
#pragma unroll
    for (int k = 0; k < 12; ++k) { GLOAD2(ua[k], h32, voa[k]); }
#pragma unroll
    for (int k = 0; k < 12; ++k) { GLOAD2(ub[k], h32, vob[k]); }
    vmwait0();

    float a0 = 0.f, a1 = 0.f, a2 = 0.f, a3 = 0.f;
    float b0 = 0.f, b1 = 0.f, b2 = 0.f, b3 = 0.f;
#pragma unroll
    for (int k = 0; k < 12; ++k) {
      float wk = (k * 4 + q < ca) ? 1.f : 0.f;
      a0 = fmaf(wk, __uint_as_float(ua[k][0] << 16), a0);
      a1 = fmaf(wk, __uint_as_float(ua[k][0] & 0xFFFF0000u), a1);
      a2 = fmaf(wk, __uint_as_float(ua[k][1] << 16), a2);
      a3 = fmaf(wk, __uint_as_float(ua[k][1] & 0xFFFF0000u), a3);
    }
#pragma unroll
    for (int k = 0; k < 12; ++k) {
      float wk = (k * 4 + q < cb) ? 1.f : 0.f;
      b0 = fmaf(wk, __uint_as_float(ub[k][0] << 16), b0);
      b1 = fmaf(wk, __uint_as_float(ub[k][0] & 0xFFFF0000u), b1);
      b2 = fmaf(wk, __uint_as_float(ub[k][1] << 16), b2);
      b3 = fmaf(wk, __uint_as_float(ub[k][1] & 0xFFFF0000u), b3);
    }

    // rare leftovers (c > 48)
    const uint2* __restrict__ h2 = (const uint2*)h32;
    for (int e0 = 48; e0 < ca; e0 += 4) {
      int e = e0 + q;
      float wk = (e < ca) ? 1.f : 0.f;
      int p = (e < ca) ? (int)bsa[e] : 0;
      uint2 u = h2[(size_t)p * 16 + hl];
      a0 = fmaf(wk, __uint_as_float(u.x << 16), a0);
      a1 = fmaf(wk, __uint_as_float(u.x & 0xFFFF0000u), a1);
      a2 = fmaf(wk, __uint_as_float(u.y << 16), a2);
      a3 = fmaf(wk, __uint_as_float(u.y & 0xFFFF0000u), a3);
    }
    for (int e0 = 48; e0 < cb; e0 += 4) {
      int e = e0 + q;
      float wk = (e < cb) ? 1.f : 0.f;
      int p = (e < cb) ? (int)bsb[e] : 0;
      uint2 u = h2[(size_t)p * 16 + hl];
      b0 = fmaf(wk, __uint_as_float(u.x << 16), b0);
      b1 = fmaf(wk, __uint_as_float(u.x & 0xFFFF0000u), b1);
      b2 = fmaf(wk, __uint_as_float(u.y << 16), b2);
      b3 = fmaf(wk, __uint_as_float(u.y & 0xFFFF0000u), b3);
    }

    a0 += __shfl_xor(a0, 16); a1 += __shfl_xor(a1, 16);
    a2 += __shfl_xor(a2, 16); a3 += __shfl_xor(a3, 16);
    b0 += __shfl_xor(b0, 16); b1 += __shfl_xor(b1, 16);
    b2 += __shfl_xor(b2, 16); b3 += __shfl_xor(b3, 16);
    a0 += __shfl_xor(a0, 32); a1 += __shfl_xor(a1, 32);
    a2 += __shfl_xor(a2, 32); a3 += __shfl_xor(a3, 32);
    b0 += __shfl_xor(b0, 32); b1 += __shfl_xor(b1, 32);
    b2 += __shfl_xor(b2, 32); b3 += __shfl_xor(b3, 32);

    if (lane < 16) {
      int na = bin * NPB + nl;
      if (na < N) {
        float inv = 1.f / fmaxf((float)ca, 1.f);
        float4 r;
        r.x = a0 * inv; r.y = a1 * inv; r.z = a2 * inv; r.w = a3 * inv;
        *(float4*)(out + (size_t)na * O_OUT + hl * 4) = r;
      }
      int nb = bin * NPB + nlb;
      if (hasb && nb < N) {
        float inv = 1.f / fmaxf((float)cb, 1.f);
        float4 r;
        r.x = b0 * inv; r.y = b1 * inv; r.z = b2 * inv; r.w = b3 * inv;
        *(float4*)(out + (size_t)nb * O_OUT + hl * 4) = r;
      }
    }
  }
}

// ---------------- launch (2 dispatches, no prep) -----------------
extern "C" void kernel_launch(void* const* d_in, const int* in_sizes, int n_in,
                              void* d_out, int out_size, void* d_ws, size_t ws_size,
                              hipStream_t stream) {
  const float* x = (const float*)d_in[0];
  const float* W = (const float*)d_in[1];
  const float* b = (const float*)d_in[2];
  const int* esrc = (const int*)d_in[3];
  const int* edst = (const int*)d_in[4];
  float* out = (float*)d_out;

  const int N = in_sizes[0] / K_IN;  // 50000
  const int E = in_sizes[3];         // 1600000
  const int npart = (E + PART_CHUNK - 1) / PART_CHUNK;  // 391
  const int ngemm = (N + 63) / 64;                      // 782

  // workspace layout (~13.6 MB)
  char* ws = (char*)d_ws;
  __hip_bfloat16* h = (__hip_bfloat16*)ws;                       // 6,400,000 B
  size_t off = (size_t)N * O_OUT * sizeof(__hip_bfloat16);
  unsigned* bucket_det = (unsigned*)(ws + off);                  // 6,406,144 B
  off += (size_t)npart * PART_CHUNK * sizeof(unsigned);
  unsigned short* scan_tab = (unsigned short*)(ws + off);        //   802,332 B

  k_fused<<<ngemm + npart, 256, 0, stream>>>(x, W, b, h, esrc, edst,
                                             bucket_det, scan_tab, N, E);
  k_sortagg<<<NBINS, 256, 0, stream>>>(bucket_det, scan_tab, (const unsigned*)h,
                                       out, N, npart);
}

// Round 12
// 149.818 us; speedup vs baseline: 1.2654x; 1.0078x over previous
//
#include <hip/hip_runtime.h>
#include <hip/hip_bf16.h>

#define K_IN 256
#define O_OUT 64
#define NBINS 1024
#define NPB 49             // nodes per bin: 1024*49 = 50176 >= 50000
#define CAP 1824           // (legacy per-bin cap, unused in det layout)
#define PART_CHUNK 4096    // edges per partition block
#define SCAN_STRIDE 1026   // u16 entries per pid in scan_tab (1025 + pad)
#define BPB 4              // bins per sortagg block
#define NPG (NPB * BPB)    // 196 nodes per block
#define CAP4 7168          // edge cap per 4-bin group (mean 6250, +11 sigma)

typedef __attribute__((ext_vector_type(8))) short short8;
typedef __attribute__((ext_vector_type(4))) float f32x4;
typedef __attribute__((ext_vector_type(2))) unsigned u32x2;

// asm gather batch for sortagg (proven R7/R8/R10/R11)
#define GLOAD2(dst, base, voff)                                          \
  asm volatile("global_load_dwordx2 %0, %1, %2"                          \
               : "=v"(dst) : "v"(voff), "s"(base))
__device__ inline void vmwait0() {
  asm volatile("s_waitcnt vmcnt(0)" ::: "memory");
  __builtin_amdgcn_sched_barrier(0);
}

__device__ inline unsigned short bf16bits(float a) {
  __hip_bfloat16 t = __float2bfloat16(a);
  return *(unsigned short*)&t;
}

__device__ inline short8 cvt8(float4 f0, float4 f1) {
  short8 r;
  r[0] = (short)bf16bits(f0.x); r[1] = (short)bf16bits(f0.y);
  r[2] = (short)bf16bits(f0.z); r[3] = (short)bf16bits(f0.w);
  r[4] = (short)bf16bits(f1.x); r[5] = (short)bf16bits(f1.y);
  r[6] = (short)bf16bits(f1.z); r[7] = (short)bf16bits(f1.w);
  return r;
}

// ---------------- shared-memory union for the fused kernel -------
struct GemmSmem {
  unsigned short wsb[64 * 256];  // 32768 B, byte ^= (row&7)<<4 swizzle
};
struct PartSmem {
  int cnt[NBINS];
  int scanb[NBINS];
  int wsum[4];
  unsigned ord[PART_CHUNK];
};  // 24592 B
union FusedSmem {
  GemmSmem g;
  PartSmem p;
};  // 32768 B

// ---------------- GEMM body (R11, unchanged) ---------------------
__device__ void gemm_body(GemmSmem& sm, int gid, const float* __restrict__ x,
                          const float* __restrict__ W,
                          const float* __restrict__ bias,
                          __hip_bfloat16* __restrict__ h, int N) {
  const int tid = threadIdx.x;
  const int lane = tid & 63;
  const int wv = tid >> 6;
  const int n0 = gid * 64;

  // stage W: 64 KB fp32 coalesced, cvt to bf16, swizzled 16 B stores
  {
#pragma unroll
    for (int r = 0; r < 8; ++r) {
      int c = r * 256 + tid;               // 8-float chunk id (2048 total)
      const float4* ps = (const float4*)(W + c * 8);
      float4 f0 = ps[0];
      float4 f1 = ps[1];
      int row = c >> 5;
      int c16 = c & 31;
      unsigned byte = (unsigned)(row * 512 + c16 * 16);
      byte ^= (unsigned)((row & 7) << 4);
      *(short8*)((char*)sm.wsb + byte) = cvt8(f0, f1);
    }
  }
  __syncthreads();

  int anode = n0 + wv * 16 + (lane & 15);
  if (anode > N - 1) anode = N - 1;  // clamp: stores guarded below
  const float* aptr = x + (size_t)anode * K_IN + (lane >> 4) * 8;

  const int brow0 = lane & 15;
  const unsigned kb = (unsigned)((lane >> 4) * 16);
  const unsigned bswz = (unsigned)((brow0 & 7) << 4);

  f32x4 acc[4] = {{0.f, 0.f, 0.f, 0.f}, {0.f, 0.f, 0.f, 0.f},
                  {0.f, 0.f, 0.f, 0.f}, {0.f, 0.f, 0.f, 0.f}};
#pragma unroll
  for (int k8 = 0; k8 < 8; ++k8) {
    float4 f0 = *(const float4*)(aptr + k8 * 32);
    float4 f1 = *(const float4*)(aptr + k8 * 32 + 4);
    short8 a = cvt8(f0, f1);
#pragma unroll
    for (int nt = 0; nt < 4; ++nt) {
      unsigned byte = (unsigned)((brow0 + nt * 16) * 512 + k8 * 64) + kb;
      byte ^= bswz;
      short8 bfr = *(const short8*)((const char*)sm.wsb + byte);
      acc[nt] = __builtin_amdgcn_mfma_f32_16x16x32_bf16(a, bfr, acc[nt], 0, 0, 0);
    }
  }

  // epilogue: bias + relu + bf16 store
  const int col = lane & 15;
  const int rbase = (lane >> 4) * 4;
#pragma unroll
  for (int nt = 0; nt < 4; ++nt) {
    float bv = bias[nt * 16 + col];
#pragma unroll
    for (int j = 0; j < 4; ++j) {
      int node = n0 + wv * 16 + rbase + j;
      if (node < N) {
        float v = fmaxf(acc[nt][j] + bv, 0.f);
        h[(size_t)node * O_OUT + nt * 16 + col] = __float2bfloat16(v);
      }
    }
  }
}

// ---------------- partition body (R11, unchanged) ----------------
// word: src[15:0] | dl[21:16] | bin[31:22]; deterministic output.
__device__ void part_body(PartSmem& sm, int pid, const int* __restrict__ esrc,
                          const int* __restrict__ edst,
                          unsigned* __restrict__ bucket_det,
                          unsigned short* __restrict__ scan_tab, int E) {
  const int tid = threadIdx.x;
  const int lane = tid & 63;
  const int wid = tid >> 6;
  const int base = pid * PART_CHUNK;

#pragma unroll
  for (int r = 0; r < 4; ++r) sm.cnt[r * 256 + tid] = 0;

  int4 s4[4], d4[4];
#pragma unroll
  for (int r = 0; r < 4; ++r) {
    int e0 = base + r * 1024 + tid * 4;
    if (e0 + 3 < E) {
      s4[r] = *(const int4*)(esrc + e0);
      d4[r] = *(const int4*)(edst + e0);
    } else {
      s4[r] = make_int4(0, 0, 0, 0);
      d4[r] = make_int4(0, 0, 0, 0);
      int* sp = (int*)&s4[r];
      int* dp = (int*)&d4[r];
      for (int j = 0; j < 4; ++j)
        if (e0 + j < E) { sp[j] = esrc[e0 + j]; dp[j] = edst[e0 + j]; }
    }
  }
  __syncthreads();  // cnt zeroing visible

  unsigned pk[16];
  int rk[16];
#pragma unroll
  for (int r = 0; r < 4; ++r) {
    const int* sp = (const int*)&s4[r];
    const int* dp = (const int*)&d4[r];
#pragma unroll
    for (int j = 0; j < 4; ++j) {
      int k = r * 4 + j;
      int e = base + r * 1024 + tid * 4 + j;
      if (e < E) {
        int d = dp[j];
        int bb = (int)__umulhi((unsigned)d, 87652394u);  // d / 49
        int dl = d - bb * NPB;
        pk[k] = ((unsigned)sp[j] & 0xFFFFu) | ((unsigned)dl << 16) |
                ((unsigned)bb << 22);
        rk[k] = atomicAdd(&sm.cnt[bb], 1);
      } else {
        rk[k] = -1;
      }
    }
  }
  __syncthreads();

  // exclusive scan over 1024 bins: thread t owns bins 4t..4t+3
  int c0 = sm.cnt[4 * tid];
  int c1 = sm.cnt[4 * tid + 1];
  int c2 = sm.cnt[4 * tid + 2];
  int c3 = sm.cnt[4 * tid + 3];
  int s = c0 + c1 + c2 + c3;
  int incl = s;
#pragma unroll
  for (int off = 1; off < 64; off <<= 1) {
    int t = __shfl_up(incl, off);
    if (lane >= off) incl += t;
  }
  if (lane == 63) sm.wsum[wid] = incl;
  __syncthreads();
  int wpre = 0;
  for (int w = 0; w < wid; ++w) wpre += sm.wsum[w];
  int excl = wpre + incl - s;
  sm.scanb[4 * tid] = excl;
  sm.scanb[4 * tid + 1] = excl + c0;
  sm.scanb[4 * tid + 2] = excl + c0 + c1;
  sm.scanb[4 * tid + 3] = excl + c0 + c1 + c2;
  __syncthreads();

#pragma unroll
  for (int k = 0; k < 16; ++k) {
    if (rk[k] >= 0) {
      int bb = (int)(pk[k] >> 22);
      sm.ord[sm.scanb[bb] + rk[k]] = pk[k];
    }
  }
  __syncthreads();

  int nv = E - base;
  if (nv > PART_CHUNK) nv = PART_CHUNK;

  unsigned* dstp = bucket_det + (size_t)pid * PART_CHUNK;
  for (int p = tid; p < nv; p += 256) dstp[p] = sm.ord[p];
  unsigned short* st = scan_tab + (size_t)pid * SCAN_STRIDE;
  for (int i = tid; i < NBINS; i += 256) st[i] = (unsigned short)sm.scanb[i];
  if (tid == 0) st[NBINS] = (unsigned short)nv;
}

// ---------------- fused heterogeneous dispatch (R11) -------------
__global__ __launch_bounds__(256, 4) void k_fused(const float* __restrict__ x,
                                                  const float* __restrict__ W,
                                                  const float* __restrict__ bias,
                                                  __hip_bfloat16* __restrict__ h,
                                                  const int* __restrict__ esrc,
                                                  const int* __restrict__ edst,
                                                  unsigned* __restrict__ bucket_det,
                                                  unsigned short* __restrict__ scan_tab,
                                                  int N, int E) {
  __shared__ FusedSmem sm;
  const int npart = (E + PART_CHUNK - 1) / PART_CHUNK;
  const int b = blockIdx.x;
  if (b % 3 == 1 && b / 3 < npart) {
    part_body(sm.p, b / 3, esrc, edst, bucket_det, scan_tab, E);
  } else {
    int skipped = (b + 2) / 3;
    if (skipped > npart) skipped = npart;
    gemm_body(sm.g, b - skipped, x, W, bias, h, N);
  }
}

// ---------------- 4-bin sortagg: 512 thr, grid 256 ---------------
// Segment [st[b0], st[b0+4]) per chunk is CONTIGUOUS (~64 B): 4x line
// amortization on both scan_tab reads and bucket_det segment reads.
__global__ __launch_bounds__(512, 1) void k_sortagg(const unsigned* __restrict__ bucket_det,
                                                    const unsigned short* __restrict__ scan_tab,
                                                    const unsigned* __restrict__ h32,
                                                    float* __restrict__ out,
                                                    int N, int npart) {
  __shared__ unsigned ord32[CAP4];            // 28672 B
  __shared__ unsigned short sbuf[CAP4 + 64];  // 14464 B
  __shared__ int hist[NPG];                   //   784 B
  __shared__ int offs[NPG];                   //   784 B
  __shared__ int wsum8[8];

  const int tid = threadIdx.x;
  const int lane = tid & 63;
  const int wid = tid >> 6;  // 0..7
  const int bg = blockIdx.x;
  const int b0 = bg * BPB;

  if (tid < NPG) hist[tid] = 0;

  // ---- phase 1: segment descriptors + block scan + contiguous copy
  int cnt_p = 0, s0 = 0;
  if (tid < npart) {
    const unsigned short* st = scan_tab + (size_t)tid * SCAN_STRIDE;
    s0 = st[b0];
    cnt_p = (int)st[b0 + BPB] - s0;  // b0+4 <= 1024 (entry 1024 = nv)
  }
  int incl = cnt_p;
#pragma unroll
  for (int off = 1; off < 64; off <<= 1) {
    int t = __shfl_up(incl, off);
    if (lane >= off) incl += t;
  }
  if (lane == 63) wsum8[wid] = incl;
  __syncthreads();
  int wpre = 0, total = 0;
#pragma unroll
  for (int w = 0; w < 8; ++w) {
    int v = wsum8[w];
    if (w < wid) wpre += v;
    total += v;
  }
  int myofs = wpre + incl - cnt_p;
  {
    const unsigned* srcp = bucket_det + (size_t)tid * PART_CHUNK + s0;
    int j = 0;
    for (; j + 4 <= cnt_p; j += 4) {
      unsigned v0 = srcp[j], v1 = srcp[j + 1], v2 = srcp[j + 2], v3 = srcp[j + 3];
      int d = myofs + j;
      if (d + 3 < CAP4) {
        ord32[d] = v0; ord32[d + 1] = v1; ord32[d + 2] = v2; ord32[d + 3] = v3;
      } else {
        if (d < CAP4) ord32[d] = v0;
        if (d + 1 < CAP4) ord32[d + 1] = v1;
        if (d + 2 < CAP4) ord32[d + 2] = v2;
        if (d + 3 < CAP4) ord32[d + 3] = v3;
      }
    }
    for (; j < cnt_p; ++j) {
      int d = myofs + j;
      if (d < CAP4) ord32[d] = srcp[j];
    }
  }
  __syncthreads();

  int cnt = total;
  if (cnt > CAP4) cnt = CAP4;

  // ---- phase 2a: histogram by group-node (bb&3)*49 + dl ----
  unsigned pk2[4][4];
  int rk2[4][4];
#pragma unroll
  for (int g = 0; g < 4; ++g) {
#pragma unroll
    for (int j = 0; j < 4; ++j) {
      int i = g * 2048 + tid * 4 + j;
      if (i < cnt) {
        unsigned w = ord32[i];
        pk2[g][j] = w;
        int gidx = (int)((w >> 22) & 3u) * NPB + (int)((w >> 16) & 63u);
        rk2[g][j] = atomicAdd(&hist[gidx], 1);
      } else {
        rk2[g][j] = -1;
      }
    }
  }
  __syncthreads();

  // ---- phase 2b: exclusive scan over 196 entries (wave 0) ----
  if (tid < 64) {
    int c0 = (4 * tid < NPG) ? hist[4 * tid] : 0;
    int c1 = (4 * tid + 1 < NPG) ? hist[4 * tid + 1] : 0;
    int c2 = (4 * tid + 2 < NPG) ? hist[4 * tid + 2] : 0;
    int c3 = (4 * tid + 3 < NPG) ? hist[4 * tid + 3] : 0;
    int s = c0 + c1 + c2 + c3;
    int inc = s;
#pragma unroll
    for (int off = 1; off < 64; off <<= 1) {
      int t = __shfl_up(inc, off);
      if (lane >= off) inc += t;
    }
    int excl = inc - s;
    if (4 * tid < NPG) offs[4 * tid] = excl;
    if (4 * tid + 1 < NPG) offs[4 * tid + 1] = excl + c0;
    if (4 * tid + 2 < NPG) offs[4 * tid + 2] = excl + c0 + c1;
    if (4 * tid + 3 < NPG) offs[4 * tid + 3] = excl + c0 + c1 + c2;
  }
  __syncthreads();

#pragma unroll
  for (int g = 0; g < 4; ++g)
#pragma unroll
    for (int j = 0; j < 4; ++j)
      if (rk2[g][j] >= 0) {
        unsigned w = pk2[g][j];
        int gidx = (int)((w >> 22) & 3u) * NPB + (int)((w >> 16) & 63u);
        sbuf[offs[gidx] + rk2[g][j]] = (unsigned short)(w & 0xFFFFu);
      }
  __syncthreads();

  // ---- phase 2c: gather + accumulate (node pairs gA, gA+98) ----
  const int q = lane >> 4;   // edge within quad
  const int hl = lane & 15;  // uint2 within h row
  const unsigned hlb = (unsigned)hl * 8u;

  for (int gA = wid; gA < NPG / 2; gA += 8) {
    const int gB = gA + NPG / 2;
    const int ca = hist[gA];
    const int cb = hist[gB];
    const unsigned short* bsa = sbuf + offs[gA];
    const unsigned short* bsb = sbuf + offs[gB];

    unsigned voa[12], vob[12];
#pragma unroll
    for (int k = 0; k < 12; ++k) {
      int e = k * 4 + q;
      unsigned pa = (e < ca) ? (unsigned)bsa[e] : 0u;
      unsigned pb = (e < cb) ? (unsigned)bsb[e] : 0u;
      voa[k] = pa * 128u + hlb;
      vob[k] = pb * 128u + hlb;
    }
    u32x2 ua[12], ub[12];
#pragma unroll
    for (int k = 0; k < 12; ++k) { GLOAD2(ua[k], h32, voa[k]); }
#pragma unroll
    for (int k = 0; k < 12; ++k) { GLOAD2(ub[k], h32, vob[k]); }
    vmwait0();

    float a0 = 0.f, a1 = 0.f, a2 = 0.f, a3 = 0.f;
    float b0f = 0.f, b1 = 0.f, b2 = 0.f, b3 = 0.f;
#pragma unroll
    for (int k = 0; k < 12; ++k) {
      float wk = (k * 4 + q < ca) ? 1.f : 0.f;
      a0 = fmaf(wk, __uint_as_float(ua[k][0] << 16), a0);
      a1 = fmaf(wk, __uint_as_float(ua[k][0] & 0xFFFF0000u), a1);
      a2 = fmaf(wk, __uint_as_float(ua[k][1] << 16), a2);
      a3 = fmaf(wk, __uint_as_float(ua[k][1] & 0xFFFF0000u), a3);
    }
#pragma unroll
    for (int k = 0; k < 12; ++k) {
      float wk = (k * 4 + q < cb) ? 1.f : 0.f;
      b0f = fmaf(wk, __uint_as_float(ub[k][0] << 16), b0f);
      b1 = fmaf(wk, __uint_as_float(ub[k][0] & 0xFFFF0000u), b1);
      b2 = fmaf(wk, __uint_as_float(ub[k][1] << 16), b2);
      b3 = fmaf(wk, __uint_as_float(ub[k][1] & 0xFFFF0000u), b3);
    }

    // rare leftovers (c > 48)
    const uint2* __restrict__ h2 = (const uint2*)h32;
    for (int e0 = 48; e0 < ca; e0 += 4) {
      int e = e0 + q;
      float wk = (e < ca) ? 1.f : 0.f;
      int p = (e < ca) ? (int)bsa[e] : 0;
      uint2 u = h2[(size_t)p * 16 + hl];
      a0 = fmaf(wk, __uint_as_float(u.x << 16), a0);
      a1 = fmaf(wk, __uint_as_float(u.x & 0xFFFF0000u), a1);
      a2 = fmaf(wk, __uint_as_float(u.y << 16), a2);
      a3 = fmaf(wk, __uint_as_float(u.y & 0xFFFF0000u), a3);
    }
    for (int e0 = 48; e0 < cb; e0 += 4) {
      int e = e0 + q;
      float wk = (e < cb) ? 1.f : 0.f;
      int p = (e < cb) ? (int)bsb[e] : 0;
      uint2 u = h2[(size_t)p * 16 + hl];
      b0f = fmaf(wk, __uint_as_float(u.x << 16), b0f);
      b1 = fmaf(wk, __uint_as_float(u.x & 0xFFFF0000u), b1);
      b2 = fmaf(wk, __uint_as_float(u.y << 16), b2);
      b3 = fmaf(wk, __uint_as_float(u.y & 0xFFFF0000u), b3);
    }

    a0 += __shfl_xor(a0, 16); a1 += __shfl_xor(a1, 16);
    a2 += __shfl_xor(a2, 16); a3 += __shfl_xor(a3, 16);
    b0f += __shfl_xor(b0f, 16); b1 += __shfl_xor(b1, 16);
    b2 += __shfl_xor(b2, 16); b3 += __shfl_xor(b3, 16);
    a0 += __shfl_xor(a0, 32); a1 += __shfl_xor(a1, 32);
    a2 += __shfl_xor(a2, 32); a3 += __shfl_xor(a3, 32);
    b0f += __shfl_xor(b0f, 32); b1 += __shfl_xor(b1, 32);
    b2 += __shfl_xor(b2, 32); b3 += __shfl_xor(b3, 32);

    if (lane < 16) {
      int na = bg * NPG + gA;
      if (na < N) {
        float inv = 1.f / fmaxf((float)ca, 1.f);
        float4 r;
        r.x = a0 * inv; r.y = a1 * inv; r.z = a2 * inv; r.w = a3 * inv;
        *(float4*)(out + (size_t)na * O_OUT + hl * 4) = r;
      }
      int nb = bg * NPG + gB;
      if (nb < N) {
        float inv = 1.f / fmaxf((float)cb, 1.f);
        float4 r;
        r.x = b0f * inv; r.y = b1 * inv; r.z = b2 * inv; r.w = b3 * inv;
        *(float4*)(out + (size_t)nb * O_OUT + hl * 4) = r;
      }
    }
  }
}

// ---------------- launch (2 dispatches) --------------------------
extern "C" void kernel_launch(void* const* d_in, const int* in_sizes, int n_in,
                              void* d_out, int out_size, void* d_ws, size_t ws_size,
                              hipStream_t stream) {
  const float* x = (const float*)d_in[0];
  const float* W = (const float*)d_in[1];
  const float* b = (const float*)d_in[2];
  const int* esrc = (const int*)d_in[3];
  const int* edst = (const int*)d_in[4];
  float* out = (float*)d_out;

  const int N = in_sizes[0] / K_IN;  // 50000
  const int E = in_sizes[3];         // 1600000
  const int npart = (E + PART_CHUNK - 1) / PART_CHUNK;  // 391
  const int ngemm = (N + 63) / 64;                      // 782

  // workspace layout (~13.6 MB)
  char* ws = (char*)d_ws;
  __hip_bfloat16* h = (__hip_bfloat16*)ws;                       // 6,400,000 B
  size_t off = (size_t)N * O_OUT * sizeof(__hip_bfloat16);
  unsigned* bucket_det = (unsigned*)(ws + off);                  // 6,406,144 B
  off += (size_t)npart * PART_CHUNK * sizeof(unsigned);
  unsigned short* scan_tab = (unsigned short*)(ws + off);        //   802,332 B

  k_fused<<<ngemm + npart, 256, 0, stream>>>(x, W, b, h, esrc, edst,
                                             bucket_det, scan_tab, N, E);
  k_sortagg<<<NBINS / BPB, 512, 0, stream>>>(bucket_det, scan_tab,
                                             (const unsigned*)h, out, N, npart);
}